// Round 4
// baseline (480.805 us; speedup 1.0000x reference)
//
#include <hip/hip_runtime.h>
#include <cstdint>
#include <cstddef>

#define B_    16
#define C_    256
#define HW_   64
#define N_    4096      // 64*64 spatial
#define K_    512
#define NROW_ 65536     // B_*N_

typedef __attribute__((ext_vector_type(8))) __bf16 bf16x8;
typedef __attribute__((ext_vector_type(4))) __bf16 bf16x4;
typedef __attribute__((ext_vector_type(4))) float floatx4;

struct P2 { float v1; int k1; float v2; int k2; };

__device__ __forceinline__ bool lexless(float v, int k, float bv, int bk) {
    return (v < bv) || (v == bv && k < bk);
}
__device__ __forceinline__ void ins2(float v, int k, float& v1, int& k1, float& v2, int& k2) {
    if (lexless(v, k, v1, k1)) { v2 = v1; k2 = k1; v1 = v; k1 = k; }
    else if (lexless(v, k, v2, k2)) { v2 = v; k2 = k; }
}

// ---------------- kernel 1: codebook prep: e2 + bf16 hi/lo planes -------------
__global__ void prep_kernel(const float* __restrict__ cb, float* __restrict__ e2,
                            __bf16* __restrict__ cbh, __bf16* __restrict__ cbl,
                            double* __restrict__ lossAcc) {
    int k = blockIdx.x, t = threadIdx.x;
    if (k == 0 && t == 0) *lossAcc = 0.0;
    float4 v = *(const float4*)(cb + (size_t)k * C_ + t * 4);
    float vv[4] = {v.x, v.y, v.z, v.w};
    bf16x4 h, l;
    float s = 0.f;
    #pragma unroll
    for (int i = 0; i < 4; ++i) {
        h[i] = (__bf16)vv[i];
        l[i] = (__bf16)(vv[i] - (float)h[i]);
        s = fmaf(vv[i], vv[i], s);
    }
    *(bf16x4*)&cbh[(size_t)k * C_ + t * 4] = h;
    *(bf16x4*)&cbl[(size_t)k * C_ + t * 4] = l;
    #pragma unroll
    for (int off = 32; off; off >>= 1) s += __shfl_down(s, off);
    if (t == 0) e2[k] = s;
}

// ---------------- kernel 2: split-bf16 MFMA GEMM + per-row top-2 --------------
// grid (Mtile=1024, chunk=2); block 256 (4 waves). Block tile: 64 rows x 256 codes
// (each wave owns a 64-code slice; cross-wave merge via LDS before the partials
// write — R2's bug was 4 waves racing on the same partials slot).
// Natural row order: row = b*4096 + s, X[row,c] = pq[b,c,s]. K-loop: 8 c-tiles of 32.
// dot = x1.e1 + x1.e2 + x2.e1 (bf16 split), accumulated fp32 in MFMA.
__launch_bounds__(256, 3)
__global__ void main_kernel(const float* __restrict__ pq,
                            const __bf16* __restrict__ cbh, const __bf16* __restrict__ cbl,
                            const float* __restrict__ e2, P2* __restrict__ partials,
                            float* __restrict__ x2) {
    const int Mtile = blockIdx.x, chunk = blockIdx.y;
    const int tid = threadIdx.x;
    const int wave = tid >> 6, lane = tid & 63;
    const int lm = lane & 15, quad = lane >> 4;
    const int b = Mtile >> 6;                 // 4096/64 rows per b
    const int s0 = (Mtile * 64) & 4095;
    const int n0 = chunk * 256;

    __shared__ __bf16 As1[64][40];   // [m][cc], pad to 40 (80 B rows, 16B-aligned)
    __shared__ __bf16 As2[64][40];
    __shared__ __bf16 Bs1[256][40];  // [n][cc]
    __shared__ __bf16 Bs2[256][40];
    __shared__ float  xs[4][64];

    floatx4 acc[4][4];
    #pragma unroll
    for (int i = 0; i < 4; ++i)
        #pragma unroll
        for (int j = 0; j < 4; ++j) acc[i][j] = (floatx4)0.f;

    // staging maps
    const int sm = tid & 63, cg = tid >> 6;           // A: row sm, c-group cg (8 c)
    const float* pqA = pq + (size_t)b * (C_ * N_) + s0 + sm;
    const __bf16* bhrow = cbh + (size_t)(n0 + tid) * C_;   // B: one row per thread
    const __bf16* blrow = cbl + (size_t)(n0 + tid) * C_;

    float x2loc = 0.f;

    for (int ct = 0; ct < 8; ++ct) {
        const int c0 = ct * 32;
        __syncthreads();
        // ---- stage A: 8 coalesced fp32 loads, split to bf16 hi/lo ----
        float av[8];
        #pragma unroll
        for (int i = 0; i < 8; ++i)
            av[i] = pqA[(size_t)(c0 + cg * 8 + i) * N_];
        bf16x8 hi, lo;
        #pragma unroll
        for (int i = 0; i < 8; ++i) {
            hi[i] = (__bf16)av[i];
            lo[i] = (__bf16)(av[i] - (float)hi[i]);
            x2loc = fmaf(av[i], av[i], x2loc);
        }
        *(bf16x8*)&As1[sm][cg * 8] = hi;
        *(bf16x8*)&As2[sm][cg * 8] = lo;
        // ---- stage B: 64 B hi + 64 B lo per thread (bf16, from prep) ----
        {
            const uint4* ph = (const uint4*)(bhrow + c0);
            const uint4* pl = (const uint4*)(blrow + c0);
            uint4 h0 = ph[0], h1 = ph[1], h2 = ph[2], h3 = ph[3];
            uint4 l0 = pl[0], l1 = pl[1], l2 = pl[2], l3 = pl[3];
            uint4* dh = (uint4*)&Bs1[tid][0];
            uint4* dl = (uint4*)&Bs2[tid][0];
            dh[0] = h0; dh[1] = h1; dh[2] = h2; dh[3] = h3;
            dl[0] = l0; dl[1] = l1; dl[2] = l2; dl[3] = l3;
        }
        __syncthreads();

        // ---- MFMA: (x1,e1), (x1,e2), (x2,e1) with frag reuse ----
        const int lk = quad * 8;
        bf16x8 a1[4], b1[4];
        #pragma unroll
        for (int mt = 0; mt < 4; ++mt) a1[mt] = *(const bf16x8*)&As1[mt * 16 + lm][lk];
        #pragma unroll
        for (int nt = 0; nt < 4; ++nt) b1[nt] = *(const bf16x8*)&Bs1[wave * 64 + nt * 16 + lm][lk];
        #pragma unroll
        for (int mt = 0; mt < 4; ++mt)
            #pragma unroll
            for (int nt = 0; nt < 4; ++nt)
                acc[mt][nt] = __builtin_amdgcn_mfma_f32_16x16x32_bf16(a1[mt], b1[nt], acc[mt][nt], 0, 0, 0);
        bf16x8 b2[4];
        #pragma unroll
        for (int nt = 0; nt < 4; ++nt) b2[nt] = *(const bf16x8*)&Bs2[wave * 64 + nt * 16 + lm][lk];
        #pragma unroll
        for (int mt = 0; mt < 4; ++mt)
            #pragma unroll
            for (int nt = 0; nt < 4; ++nt)
                acc[mt][nt] = __builtin_amdgcn_mfma_f32_16x16x32_bf16(a1[mt], b2[nt], acc[mt][nt], 0, 0, 0);
        bf16x8 a2[4];
        #pragma unroll
        for (int mt = 0; mt < 4; ++mt) a2[mt] = *(const bf16x8*)&As2[mt * 16 + lm][lk];
        #pragma unroll
        for (int mt = 0; mt < 4; ++mt)
            #pragma unroll
            for (int nt = 0; nt < 4; ++nt)
                acc[mt][nt] = __builtin_amdgcn_mfma_f32_16x16x32_bf16(a2[mt], b1[nt], acc[mt][nt], 0, 0, 0);
    }

    __syncthreads();          // drain K-loop LDS reads (As1 is reused below)
    xs[cg][sm] = x2loc;

    // ---- epilogue: per-wave top-2 over its 64 codes -> LDS cross-wave merge ----
    P2* mergebuf = (P2*)&As1[0][0];   // 4*64*16 B = 4 KB, overlays dead As1

    const int kbase = n0 + wave * 64;
    float e2v[4];
    #pragma unroll
    for (int nt = 0; nt < 4; ++nt) e2v[nt] = e2[kbase + nt * 16 + lm];

    #pragma unroll
    for (int mt = 0; mt < 4; ++mt) {
        #pragma unroll
        for (int r = 0; r < 4; ++r) {
            float v1 = __builtin_inff(), v2 = __builtin_inff();
            int k1 = 0x7fffffff, k2 = 0x7fffffff;
            #pragma unroll
            for (int nt = 0; nt < 4; ++nt) {
                float v = fmaf(-2.f, acc[mt][nt][r], e2v[nt]);
                ins2(v, kbase + nt * 16 + lm, v1, k1, v2, k2);
            }
            #pragma unroll
            for (int m = 1; m < 16; m <<= 1) {
                float ov1 = __shfl_xor(v1, m); int ok1 = __shfl_xor(k1, m);
                float ov2 = __shfl_xor(v2, m); int ok2 = __shfl_xor(k2, m);
                ins2(ov1, ok1, v1, k1, v2, k2);
                ins2(ov2, ok2, v1, k1, v2, k2);
            }
            if (lm == 0) {
                P2 p; p.v1 = v1; p.k1 = k1; p.v2 = v2; p.k2 = k2;
                mergebuf[wave * 64 + mt * 16 + quad * 4 + r] = p;
            }
        }
    }
    __syncthreads();          // mergebuf + xs visible

    if (tid < 64) {
        float v1 = __builtin_inff(), v2 = __builtin_inff();
        int k1 = 0x7fffffff, k2 = 0x7fffffff;
        #pragma unroll
        for (int w = 0; w < 4; ++w) {
            P2 p = mergebuf[w * 64 + tid];
            ins2(p.v1, p.k1, v1, k1, v2, k2);
            ins2(p.v2, p.k2, v1, k1, v2, k2);
        }
        P2 p; p.v1 = v1; p.k1 = k1; p.v2 = v2; p.k2 = k2;
        partials[(size_t)chunk * NROW_ + Mtile * 64 + tid] = p;
        if (chunk == 0)
            x2[Mtile * 64 + tid] = xs[0][tid] + xs[1][tid] + xs[2][tid] + xs[3][tid];
    }
}

// ---------------- kernel 3: merge chunks, fp64 refine near-ties, loss --------
#define MARGIN 0.1f
__global__ void merge_kernel(const P2* __restrict__ partials, const float* __restrict__ x2,
                             const float* __restrict__ pq, const float* __restrict__ cb,
                             int* __restrict__ idx, double* __restrict__ lossAcc) {
    int row = blockIdx.x * 256 + threadIdx.x;      // natural: b*4096 + s
    float v1 = __builtin_inff(), v2 = __builtin_inff();
    int k1 = 0x7fffffff, k2 = 0x7fffffff;
    #pragma unroll
    for (int c = 0; c < 2; ++c) {
        P2 p = partials[(size_t)c * NROW_ + row];
        ins2(p.v1, p.k1, v1, k1, v2, k2);
        ins2(p.v2, p.k2, v1, k1, v2, k2);
    }
    int b = row >> 12, s = row & 4095;
    int kwin = k1;
    double d2min;
    if (v2 - v1 < MARGIN) {
        // exact fp64 re-evaluation of both candidates (rare path)
        const float* xp  = pq + (size_t)b * (C_ * N_) + s;
        const float* ca  = cb + (size_t)k1 * C_;
        const float* cbp = cb + (size_t)k2 * C_;
        double da = 0.0, db = 0.0;
        for (int c = 0; c < C_; ++c) {
            double xv = (double)xp[(size_t)c * N_];
            double ea = xv - (double)ca[c];  da += ea * ea;
            double eb = xv - (double)cbp[c]; db += eb * eb;
        }
        if (db < da || (db == da && k2 < k1)) { kwin = k2; d2min = db; }
        else d2min = da;
    } else {
        d2min = (double)(x2[row] + v1);
    }
    // reference index order: sigma(s) swaps the two 6-bit spatial halves
    int sig = ((s & 63) << 6) | (s >> 6);
    idx[(b << 12) | sig] = kwin;
    // block-reduce loss partial, one f64 atomic per block
    double sd = d2min;
    #pragma unroll
    for (int off = 32; off; off >>= 1) sd += __shfl_down(sd, off);
    __shared__ double ls[4];
    if ((threadIdx.x & 63) == 0) ls[threadIdx.x >> 6] = sd;
    __syncthreads();
    if (threadIdx.x == 0) atomicAdd(lossAcc, ls[0] + ls[1] + ls[2] + ls[3]);
}

// ---------------- kernel 4: gather codebook rows -> output (+ loss finalize) --
__global__ void scatter_kernel(const float* __restrict__ cb, const int* __restrict__ idx,
                               const double* __restrict__ lossAcc, float* __restrict__ out) {
    int ntile = blockIdx.x, b = blockIdx.y, tid = threadIdx.x;
    __shared__ int idxs[64];
    __shared__ float tile[64][65];
    if (tid < 64) idxs[tid] = idx[b * N_ + ntile * 64 + tid];
    if (b == 0 && ntile == 0 && tid == 0)
        out[(size_t)B_ * C_ * N_] =
            (float)(1.25 * (*lossAcc) / (double)((size_t)B_ * N_ * C_));
    __syncthreads();
    for (int cc = 0; cc < 4; ++cc) {
        int c0 = cc * 64;
        #pragma unroll
        for (int p = 0; p < 16; ++p) {
            int i = p * 4 + (tid >> 6);
            int c = tid & 63;
            tile[i][c] = cb[(size_t)idxs[i] * C_ + c0 + c];
        }
        __syncthreads();
        #pragma unroll
        for (int p = 0; p < 16; ++p) {
            int cl = p * 4 + (tid >> 6);
            int nl = tid & 63;
            out[((size_t)(b * C_ + c0 + cl)) * N_ + ntile * 64 + nl] = tile[nl][cl];
        }
        __syncthreads();
    }
}

// ---------------- launch ------------------------------------------------------
extern "C" void kernel_launch(void* const* d_in, const int* in_sizes, int n_in,
                              void* d_out, int out_size, void* d_ws, size_t ws_size,
                              hipStream_t stream) {
    const float* pq = (const float*)d_in[0];   // [16,256,64,64]
    const float* cb = (const float*)d_in[1];   // [512,256]
    float* out = (float*)d_out;                // 4194304 out + 1 loss
    char* ws = (char*)d_ws;
    double* lossAcc = (double*)ws;                          // 16 B
    float*  e2   = (float*)(ws + 16);                       // 2 KB
    __bf16* cbh  = (__bf16*)(ws + 16 + 2048);               // 256 KB
    __bf16* cbl  = (__bf16*)(ws + 16 + 2048 + 262144);      // 256 KB
    float*  x2   = (float*)(ws + 16 + 2048 + 2*262144);     // 256 KB
    int*    idx  = (int*)(ws + 16 + 2048 + 3*262144);       // 256 KB
    P2* partials = (P2*)(ws + 16 + 2048 + 4*262144);        // 2 MB

    prep_kernel<<<K_, 64, 0, stream>>>(cb, e2, cbh, cbl, lossAcc);
    main_kernel<<<dim3(1024, 2), 256, 0, stream>>>(pq, cbh, cbl, e2, partials, x2);
    merge_kernel<<<NROW_ / 256, 256, 0, stream>>>(partials, x2, pq, cb, idx, lossAcc);
    scatter_kernel<<<dim3(HW_, B_), 256, 0, stream>>>(cb, idx, lossAcc, out);
}